// Round 1
// baseline (2820.616 us; speedup 1.0000x reference)
//
#include <hip/hip_runtime.h>
#include <hip/hip_bf16.h>

// ImprovedGNN: 3x GCNConv(+BN eval+LeakyReLU+residual) -> mean-pool -> MLP -> L2 norm
// Strategy:
//  - deg/dinv computed ONCE (identical across layers, includes self-loop +1)
//  - CSR (by dst) built once per call: count -> 1-block scan -> atomic fill
//  - per layer: GEMM (fp32 vector, LDS-tiled, fused dinv row-scale) then
//    gather-sum over CSR with fused  t = acc*dinv*A[j] + C[j]; lrelu; +residual
//    where A/C fold bias+BatchNorm(eval).
//  - pool: sorted-batch chunked accumulation, few atomics; head: 64 blocks.

#define NNODE 100000
#define NEDGE 1600000
#define HDIM  128
#define GDIM  64
#define DDIM  64

__global__ void k_count(const int* __restrict__ dst, int e, int* __restrict__ cnt) {
    int i = blockIdx.x * blockDim.x + threadIdx.x;
    if (i < e) atomicAdd(&cnt[dst[i]], 1);
}

__global__ void k_dinv(const int* __restrict__ cnt, float* __restrict__ dinv, int n) {
    int i = blockIdx.x * blockDim.x + threadIdx.x;
    if (i < n) dinv[i] = rsqrtf((float)cnt[i] + 1.0f);   // +1 = self loop
}

__global__ __launch_bounds__(1024) void k_scan(const int* __restrict__ cnt,
                                               int* __restrict__ rowptr, int n) {
    __shared__ int partial[1024];
    int tid = threadIdx.x;
    int chunk = (n + 1023) >> 10;
    int lo = tid * chunk, hi = min(lo + chunk, n);
    int s = 0;
    for (int v = lo; v < hi; ++v) s += cnt[v];
    partial[tid] = s;
    __syncthreads();
    for (int off = 1; off < 1024; off <<= 1) {
        int t = (tid >= off) ? partial[tid - off] : 0;
        __syncthreads();
        partial[tid] += t;
        __syncthreads();
    }
    int run = (tid > 0) ? partial[tid - 1] : 0;
    for (int v = lo; v < hi; ++v) { rowptr[v] = run; run += cnt[v]; }
    if (tid == 1023) rowptr[n] = partial[1023];
}

__global__ void k_fill(const int* __restrict__ src, const int* __restrict__ dst, int e,
                       const int* __restrict__ rowptr, int* __restrict__ fill,
                       int* __restrict__ csrc) {
    int i = blockIdx.x * blockDim.x + threadIdx.x;
    if (i < e) {
        int d = dst[i];
        int pos = rowptr[d] + atomicAdd(&fill[d], 1);
        csrc[pos] = src[i];
    }
}

__global__ void k_bnprep(const float* __restrict__ b, const float* __restrict__ g,
                         const float* __restrict__ be, const float* __restrict__ m,
                         const float* __restrict__ v, float* __restrict__ A,
                         float* __restrict__ C) {
    int j = threadIdx.x;
    float sc = g[j] * rsqrtf(v[j] + 1e-5f);
    A[j] = sc;
    C[j] = (b[j] - m[j]) * sc + be[j];
}

// hs[r][:] = (X[r][:] @ W) * dinv[r].   X:[n,128] W:[128,128]
// BM=128 rows/block, 512 threads, BK=64 (2 k-tiles), 8x4 register blocking.
__global__ __launch_bounds__(512, 4) void k_gemm_scale(const float* __restrict__ X,
                                                       const float* __restrict__ W,
                                                       const float* __restrict__ dinv,
                                                       float* __restrict__ HS, int n) {
    __shared__ float ws[64 * 128];   // W[kk][j]  32KB
    __shared__ float xs[128 * 64];   // x[r][kk]  32KB
    int tid = threadIdx.x;
    int row0 = blockIdx.x * 128;
    int cg = tid & 31;    // cols 4*cg..4*cg+3
    int rg = tid >> 5;    // rows rg*8..rg*8+7
    float acc[8][4] = {};
    const float4* X4 = (const float4*)X;
    const float4* W4 = (const float4*)W;
    float4* ws4 = (float4*)ws;
    float4* xs4 = (float4*)xs;
    for (int kt = 0; kt < 2; ++kt) {
        // stage W rows [kt*64, kt*64+64): 2048 float4
        #pragma unroll
        for (int t = 0; t < 4; ++t) {
            int idx = tid + t * 512;
            int r = idx >> 5, c = idx & 31;
            ws4[idx] = W4[(kt * 64 + r) * 32 + c];
        }
        // stage X tile [row0..row0+128) x [kt*64, +64): 2048 float4 (16/row)
        #pragma unroll
        for (int t = 0; t < 4; ++t) {
            int idx = tid + t * 512;
            int r = idx >> 4, c4 = idx & 15;
            int gr = row0 + r;
            xs4[idx] = (gr < n) ? X4[gr * 32 + kt * 16 + c4] : make_float4(0.f, 0.f, 0.f, 0.f);
        }
        __syncthreads();
        #pragma unroll
        for (int k4 = 0; k4 < 16; ++k4) {
            float4 w0 = *(const float4*)&ws[(k4 * 4 + 0) * 128 + cg * 4];
            float4 w1 = *(const float4*)&ws[(k4 * 4 + 1) * 128 + cg * 4];
            float4 w2 = *(const float4*)&ws[(k4 * 4 + 2) * 128 + cg * 4];
            float4 w3 = *(const float4*)&ws[(k4 * 4 + 3) * 128 + cg * 4];
            #pragma unroll
            for (int i = 0; i < 8; ++i) {
                float4 xv = *(const float4*)&xs[(rg * 8 + i) * 64 + k4 * 4];
                acc[i][0] += xv.x * w0.x + xv.y * w1.x + xv.z * w2.x + xv.w * w3.x;
                acc[i][1] += xv.x * w0.y + xv.y * w1.y + xv.z * w2.y + xv.w * w3.y;
                acc[i][2] += xv.x * w0.z + xv.y * w1.z + xv.z * w2.z + xv.w * w3.z;
                acc[i][3] += xv.x * w0.w + xv.y * w1.w + xv.z * w2.w + xv.w * w3.w;
            }
        }
        __syncthreads();
    }
    #pragma unroll
    for (int i = 0; i < 8; ++i) {
        int gr = row0 + rg * 8 + i;
        if (gr < n) {
            float dv = dinv[gr];
            float4 o = make_float4(acc[i][0] * dv, acc[i][1] * dv,
                                   acc[i][2] * dv, acc[i][3] * dv);
            *(float4*)&HS[gr * 128 + cg * 4] = o;
        }
    }
}

// out[v] = lrelu( (hs[v]+sum_{incoming} hs[src]) * dinv[v] * A[j] + C[j] ) (+ res[v])
__global__ __launch_bounds__(256) void k_aggr(const float* __restrict__ hs,
                                              const int* __restrict__ rowptr,
                                              const int* __restrict__ csrc,
                                              const float* __restrict__ dinv,
                                              const float* __restrict__ A,
                                              const float* __restrict__ C,
                                              const float* __restrict__ res,
                                              float* __restrict__ xout, int n) {
    int node = blockIdx.x * 4 + (threadIdx.x >> 6);
    if (node >= n) return;
    int lane = threadIdx.x & 63;
    const float2* hs2 = (const float2*)hs;
    float2 acc = hs2[node * 64 + lane];   // self loop
    int e = rowptr[node], end = rowptr[node + 1];
    for (; e + 4 <= end; e += 4) {
        int s0 = csrc[e], s1 = csrc[e + 1], s2 = csrc[e + 2], s3 = csrc[e + 3];
        float2 t0 = hs2[s0 * 64 + lane];
        float2 t1 = hs2[s1 * 64 + lane];
        float2 t2 = hs2[s2 * 64 + lane];
        float2 t3 = hs2[s3 * 64 + lane];
        acc.x += t0.x + t1.x + t2.x + t3.x;
        acc.y += t0.y + t1.y + t2.y + t3.y;
    }
    for (; e < end; ++e) {
        int s = csrc[e];
        float2 t = hs2[s * 64 + lane];
        acc.x += t.x; acc.y += t.y;
    }
    float dv = dinv[node];
    float2 a2 = ((const float2*)A)[lane];
    float2 c2 = ((const float2*)C)[lane];
    float t0 = acc.x * dv * a2.x + c2.x;
    float t1 = acc.y * dv * a2.y + c2.y;
    t0 = (t0 >= 0.f) ? t0 : 0.01f * t0;
    t1 = (t1 >= 0.f) ? t1 : 0.01f * t1;
    if (res) {
        float2 r = ((const float2*)res)[node * 64 + lane];
        t0 += r.x; t1 += r.y;
    }
    ((float2*)xout)[node * 64 + lane] = make_float2(t0, t1);
}

// lb[g] = first index with batch[idx] >= g  (batch sorted ascending), g in [0,64]
__global__ void k_bounds(const int* __restrict__ batch, int n, int* __restrict__ lb) {
    int g = threadIdx.x;
    if (g > GDIM) return;
    int lo = 0, hi = n;
    while (lo < hi) {
        int mid = (lo + hi) >> 1;
        if (batch[mid] < g) lo = mid + 1; else hi = mid;
    }
    lb[g] = lo;
}

// chunked sorted-batch pooling: few atomics per block
__global__ __launch_bounds__(128) void k_pool(const float* __restrict__ x3,
                                              const int* __restrict__ batch,
                                              float* __restrict__ pool, int n) {
    int start = blockIdx.x * 256;
    int end = min(start + 256, n);
    int j = threadIdx.x;
    float acc = 0.f;
    int cur = batch[start];
    for (int v = start; v < end; ++v) {
        int g = batch[v];
        if (g != cur) {
            atomicAdd(&pool[cur * 128 + j], acc);
            acc = 0.f; cur = g;
        }
        acc += x3[(size_t)v * 128 + j];
    }
    atomicAdd(&pool[cur * 128 + j], acc);
}

__global__ __launch_bounds__(128) void k_head(const float* __restrict__ pool,
                                              const int* __restrict__ lb,
                                              const float* __restrict__ fcW1,
                                              const float* __restrict__ fcb1,
                                              const float* __restrict__ fcW2,
                                              const float* __restrict__ fcb2,
                                              float* __restrict__ out) {
    int g = blockIdx.x;
    int j = threadIdx.x;
    __shared__ float ph[128];
    __shared__ float hh[128];
    float cnt = (float)(lb[g + 1] - lb[g]);
    float inv = 1.0f / fmaxf(cnt, 1.0f);
    ph[j] = pool[g * 128 + j] * inv;
    __syncthreads();
    float a = fcb1[j];
    for (int k = 0; k < 128; ++k) a += ph[k] * fcW1[k * 128 + j];
    hh[j] = (a >= 0.f) ? a : 0.01f * a;
    __syncthreads();
    if (j < DDIM) {
        float o = fcb2[j];
        for (int k = 0; k < 128; ++k) o += hh[k] * fcW2[k * DDIM + j];
        float ss = o * o;
        #pragma unroll
        for (int off = 32; off > 0; off >>= 1) ss += __shfl_xor(ss, off);
        float nrm = sqrtf(ss);
        out[g * DDIM + j] = o / fmaxf(nrm, 1e-12f);
    }
}

extern "C" void kernel_launch(void* const* d_in, const int* in_sizes, int n_in,
                              void* d_out, int out_size, void* d_ws, size_t ws_size,
                              hipStream_t stream) {
    const float* x      = (const float*)d_in[0];
    const int*   ei     = (const int*)d_in[1];
    const int*   batch  = (const int*)d_in[2];
    const float* W1     = (const float*)d_in[3];
    const float* b1     = (const float*)d_in[4];
    const float* W2     = (const float*)d_in[5];
    const float* b2     = (const float*)d_in[6];
    const float* W3     = (const float*)d_in[7];
    const float* b3     = (const float*)d_in[8];
    const float* g1     = (const float*)d_in[9];
    const float* be1    = (const float*)d_in[10];
    const float* m1     = (const float*)d_in[11];
    const float* v1     = (const float*)d_in[12];
    const float* g2     = (const float*)d_in[13];
    const float* be2    = (const float*)d_in[14];
    const float* m2     = (const float*)d_in[15];
    const float* v2     = (const float*)d_in[16];
    const float* g3     = (const float*)d_in[17];
    const float* be3    = (const float*)d_in[18];
    const float* m3     = (const float*)d_in[19];
    const float* v3     = (const float*)d_in[20];
    const float* fcW1   = (const float*)d_in[21];
    const float* fcb1   = (const float*)d_in[22];
    const float* fcW2   = (const float*)d_in[23];
    const float* fcb2   = (const float*)d_in[24];
    float* out = (float*)d_out;

    const int N = in_sizes[0] / HDIM;       // 100000
    const int E = in_sizes[1] / 2;          // 1600000
    const int* srcp = ei;
    const int* dstp = ei + E;

    // ---- workspace layout (512B aligned) ----
    char* base = (char*)d_ws;
    size_t off = 0;
    auto alloc = [&](size_t bytes) -> char* {
        char* p = base + off;
        off += (bytes + 511) & ~(size_t)511;
        return p;
    };
    int*   degcnt = (int*)  alloc((size_t)N * 4);
    int*   fill   = (int*)  alloc((size_t)N * 4);
    int*   rowptr = (int*)  alloc((size_t)(N + 1) * 4);
    int*   csrc   = (int*)  alloc((size_t)E * 4);
    float* dinv   = (float*)alloc((size_t)N * 4);
    float* AC     = (float*)alloc(3 * 256 * 4);
    int*   lb     = (int*)  alloc((GDIM + 1) * 4);
    float* pool   = (float*)alloc(GDIM * HDIM * 4);
    float* hs     = (float*)alloc((size_t)N * HDIM * 4);
    float* bufA   = (float*)alloc((size_t)N * HDIM * 4);
    float* bufB   = (float*)alloc((size_t)N * HDIM * 4);
    if (off > ws_size) return;  // workspace too small -> fail validation loudly

    // ---- zero-init counters/accumulators ----
    hipMemsetAsync(degcnt, 0, (size_t)N * 4, stream);
    hipMemsetAsync(fill,   0, (size_t)N * 4, stream);
    hipMemsetAsync(pool,   0, GDIM * HDIM * 4, stream);

    // ---- graph structure (once, reused by all 3 layers) ----
    k_bounds<<<1, 128, 0, stream>>>(batch, N, lb);
    k_count<<<(E + 255) / 256, 256, 0, stream>>>(dstp, E, degcnt);
    k_dinv<<<(N + 255) / 256, 256, 0, stream>>>(degcnt, dinv, N);
    k_scan<<<1, 1024, 0, stream>>>(degcnt, rowptr, N);
    k_fill<<<(E + 255) / 256, 256, 0, stream>>>(srcp, dstp, E, rowptr, fill, csrc);

    // ---- fold bias+BN(eval) into per-channel A,C ----
    k_bnprep<<<1, 128, 0, stream>>>(b1, g1, be1, m1, v1, AC + 0 * 256, AC + 0 * 256 + 128);
    k_bnprep<<<1, 128, 0, stream>>>(b2, g2, be2, m2, v2, AC + 1 * 256, AC + 1 * 256 + 128);
    k_bnprep<<<1, 128, 0, stream>>>(b3, g3, be3, m3, v3, AC + 2 * 256, AC + 2 * 256 + 128);

    int gemmBlocks = (N + 127) / 128;
    int aggrBlocks = (N + 3) / 4;

    // layer 1: x -> bufA
    k_gemm_scale<<<gemmBlocks, 512, 0, stream>>>(x, W1, dinv, hs, N);
    k_aggr<<<aggrBlocks, 256, 0, stream>>>(hs, rowptr, csrc, dinv,
                                           AC + 0 * 256, AC + 0 * 256 + 128,
                                           nullptr, bufA, N);
    // layer 2: bufA -> bufB (+bufA residual)
    k_gemm_scale<<<gemmBlocks, 512, 0, stream>>>(bufA, W2, dinv, hs, N);
    k_aggr<<<aggrBlocks, 256, 0, stream>>>(hs, rowptr, csrc, dinv,
                                           AC + 1 * 256, AC + 1 * 256 + 128,
                                           bufA, bufB, N);
    // layer 3: bufB -> bufA (+bufB residual)
    k_gemm_scale<<<gemmBlocks, 512, 0, stream>>>(bufB, W3, dinv, hs, N);
    k_aggr<<<aggrBlocks, 256, 0, stream>>>(hs, rowptr, csrc, dinv,
                                           AC + 2 * 256, AC + 2 * 256 + 128,
                                           bufB, bufA, N);

    // ---- pool + head ----
    k_pool<<<(N + 255) / 256, 128, 0, stream>>>(bufA, batch, pool, N);
    k_head<<<GDIM, 128, 0, stream>>>(pool, lb, fcW1, fcb1, fcW2, fcb2, out);
}

// Round 5
// 2072.246 us; speedup vs baseline: 1.3611x; 1.3611x over previous
//
#include <hip/hip_runtime.h>
#include <hip/hip_bf16.h>

// ImprovedGNN: 3x GCNConv(+BN eval+LeakyReLU+residual) -> mean-pool -> MLP -> L2 norm
//  - deg/dinv computed ONCE (identical across layers, self-loop +1 included)
//  - CSR (by dst) built once per call: count -> 3-phase vectorized scan -> atomic fill
//  - per layer: fp32 LDS-tiled GEMM (fused dinv row-scale), then CSR gather-sum
//    with fused  t = acc*dinv*A[j] + C[j]; lrelu; +residual  (A/C fold bias+BN eval)
//  - R1 post-mortem: __launch_bounds__(512,4) capped VGPRs at 64 -> accumulator
//    spill to scratch (1.8GB HBM traffic/dispatch, VALUBusy 4.7%). Relaxed to
//    (512,2); LDS (64KB) already limits to 2 blocks/CU so no occupancy loss.
//  - R2/R3/R4: infra timeouts, never measured. Resubmitting unchanged.

#define HDIM  128
#define GDIM  64
#define DDIM  64

__global__ void k_count(const int* __restrict__ dst, int e, int* __restrict__ cnt) {
    int i = blockIdx.x * blockDim.x + threadIdx.x;
    if (i < e) atomicAdd(&cnt[dst[i]], 1);
}

// ---- 3-phase exclusive scan of cnt -> rowptr, dinv folded into phase A ----
// phase A: 256 int4 per block (1024 ints); block sum -> bsum[b]; dinv[i]=rsqrt(cnt+1)
__global__ __launch_bounds__(256) void k_scan_a(const int* __restrict__ cnt,
                                                int* __restrict__ bsum,
                                                float* __restrict__ dinv, int n) {
    int b = blockIdx.x, t = threadIdx.x;
    int i4 = b * 256 + t, base = i4 * 4;
    int4 v = make_int4(0, 0, 0, 0);
    if (base + 3 < n) {
        v = ((const int4*)cnt)[i4];
        float4 dv = make_float4(rsqrtf((float)v.x + 1.f), rsqrtf((float)v.y + 1.f),
                                rsqrtf((float)v.z + 1.f), rsqrtf((float)v.w + 1.f));
        ((float4*)dinv)[i4] = dv;
    } else {
        if (base + 0 < n) { v.x = cnt[base + 0]; dinv[base + 0] = rsqrtf((float)v.x + 1.f); }
        if (base + 1 < n) { v.y = cnt[base + 1]; dinv[base + 1] = rsqrtf((float)v.y + 1.f); }
        if (base + 2 < n) { v.z = cnt[base + 2]; dinv[base + 2] = rsqrtf((float)v.z + 1.f); }
        if (base + 3 < n) { v.w = cnt[base + 3]; dinv[base + 3] = rsqrtf((float)v.w + 1.f); }
    }
    __shared__ int red[256];
    red[t] = v.x + v.y + v.z + v.w;
    __syncthreads();
    #pragma unroll
    for (int off = 128; off > 0; off >>= 1) {
        if (t < off) red[t] += red[t + off];
        __syncthreads();
    }
    if (t == 0) bsum[b] = red[0];
}

// phase B: single block scans bsum[nb] -> boff (exclusive); writes rowptr[n]=total
__global__ __launch_bounds__(128) void k_scan_b(const int* __restrict__ bsum, int nb,
                                                int* __restrict__ boff,
                                                int* __restrict__ rowptr, int n) {
    __shared__ int sh[128];
    int t = threadIdx.x;
    int v = (t < nb) ? bsum[t] : 0;
    sh[t] = v;
    __syncthreads();
    #pragma unroll
    for (int off = 1; off < 128; off <<= 1) {
        int u = (t >= off) ? sh[t - off] : 0;
        __syncthreads();
        sh[t] += u;
        __syncthreads();
    }
    boff[t] = sh[t] - v;
    if (t == 127) rowptr[n] = sh[127];
}

// phase C: re-read cnt, intra-block scan, write rowptr
__global__ __launch_bounds__(256) void k_scan_c(const int* __restrict__ cnt,
                                                const int* __restrict__ boff,
                                                int* __restrict__ rowptr, int n) {
    int b = blockIdx.x, t = threadIdx.x;
    int i4 = b * 256 + t, base = i4 * 4;
    int4 v = make_int4(0, 0, 0, 0);
    if (base + 3 < n) v = ((const int4*)cnt)[i4];
    else {
        if (base + 0 < n) v.x = cnt[base + 0];
        if (base + 1 < n) v.y = cnt[base + 1];
        if (base + 2 < n) v.z = cnt[base + 2];
        if (base + 3 < n) v.w = cnt[base + 3];
    }
    int s = v.x + v.y + v.z + v.w;
    __shared__ int sh[256];
    sh[t] = s;
    __syncthreads();
    #pragma unroll
    for (int off = 1; off < 256; off <<= 1) {
        int u = (t >= off) ? sh[t - off] : 0;
        __syncthreads();
        sh[t] += u;
        __syncthreads();
    }
    int excl = sh[t] - s + boff[b];
    if (base + 3 < n) {
        ((int4*)rowptr)[i4] = make_int4(excl, excl + v.x, excl + v.x + v.y,
                                        excl + v.x + v.y + v.z);
    } else {
        if (base + 0 < n) rowptr[base + 0] = excl;
        if (base + 1 < n) rowptr[base + 1] = excl + v.x;
        if (base + 2 < n) rowptr[base + 2] = excl + v.x + v.y;
        if (base + 3 < n) rowptr[base + 3] = excl + v.x + v.y + v.z;
    }
}

__global__ void k_fill(const int* __restrict__ src, const int* __restrict__ dst, int e,
                       const int* __restrict__ rowptr, int* __restrict__ fill,
                       int* __restrict__ csrc) {
    int i = blockIdx.x * blockDim.x + threadIdx.x;
    if (i < e) {
        int d = dst[i];
        int pos = rowptr[d] + atomicAdd(&fill[d], 1);
        csrc[pos] = src[i];
    }
}

// fold bias+BN(eval) into per-channel A,C for all 3 layers (block l = layer l)
__global__ void k_bnprep(const float* __restrict__ b1, const float* __restrict__ g1,
                         const float* __restrict__ be1, const float* __restrict__ m1,
                         const float* __restrict__ v1,
                         const float* __restrict__ b2, const float* __restrict__ g2,
                         const float* __restrict__ be2, const float* __restrict__ m2,
                         const float* __restrict__ v2,
                         const float* __restrict__ b3, const float* __restrict__ g3,
                         const float* __restrict__ be3, const float* __restrict__ m3,
                         const float* __restrict__ v3,
                         float* __restrict__ AC) {
    int l = blockIdx.x, j = threadIdx.x;
    const float* b  = (l == 0) ? b1  : (l == 1) ? b2  : b3;
    const float* g  = (l == 0) ? g1  : (l == 1) ? g2  : g3;
    const float* be = (l == 0) ? be1 : (l == 1) ? be2 : be3;
    const float* m  = (l == 0) ? m1  : (l == 1) ? m2  : m3;
    const float* v  = (l == 0) ? v1  : (l == 1) ? v2  : v3;
    float sc = g[j] * rsqrtf(v[j] + 1e-5f);
    AC[l * 256 + j] = sc;
    AC[l * 256 + 128 + j] = (b[j] - m[j]) * sc + be[j];
}

// hs[r][:] = (X[r][:] @ W) * dinv[r].   X:[n,128] W:[128,128]
// BM=128 rows/block, 512 threads, BK=64 (2 k-tiles), 8x4 register blocking.
// launch_bounds (512,2): VGPR cap >=128 (acc needs ~80); LDS limits 2 blocks/CU.
__global__ __launch_bounds__(512, 2) void k_gemm_scale(const float* __restrict__ X,
                                                       const float* __restrict__ W,
                                                       const float* __restrict__ dinv,
                                                       float* __restrict__ HS, int n) {
    __shared__ float ws[64 * 128];   // W[kk][j]  32KB
    __shared__ float xs[128 * 64];   // x[r][kk]  32KB
    int tid = threadIdx.x;
    int row0 = blockIdx.x * 128;
    int cg = tid & 31;    // cols 4*cg..4*cg+3
    int rg = tid >> 5;    // rows rg*8..rg*8+7
    float acc[8][4] = {};
    const float4* X4 = (const float4*)X;
    const float4* W4 = (const float4*)W;
    float4* ws4 = (float4*)ws;
    float4* xs4 = (float4*)xs;
    for (int kt = 0; kt < 2; ++kt) {
        #pragma unroll
        for (int t = 0; t < 4; ++t) {
            int idx = tid + t * 512;
            int r = idx >> 5, c = idx & 31;
            ws4[idx] = W4[(kt * 64 + r) * 32 + c];
        }
        #pragma unroll
        for (int t = 0; t < 4; ++t) {
            int idx = tid + t * 512;
            int r = idx >> 4, c4 = idx & 15;
            int gr = row0 + r;
            xs4[idx] = (gr < n) ? X4[gr * 32 + kt * 16 + c4] : make_float4(0.f, 0.f, 0.f, 0.f);
        }
        __syncthreads();
        #pragma unroll
        for (int k4 = 0; k4 < 16; ++k4) {
            float4 w0 = *(const float4*)&ws[(k4 * 4 + 0) * 128 + cg * 4];
            float4 w1 = *(const float4*)&ws[(k4 * 4 + 1) * 128 + cg * 4];
            float4 w2 = *(const float4*)&ws[(k4 * 4 + 2) * 128 + cg * 4];
            float4 w3 = *(const float4*)&ws[(k4 * 4 + 3) * 128 + cg * 4];
            #pragma unroll
            for (int i = 0; i < 8; ++i) {
                float4 xv = *(const float4*)&xs[(rg * 8 + i) * 64 + k4 * 4];
                acc[i][0] += xv.x * w0.x + xv.y * w1.x + xv.z * w2.x + xv.w * w3.x;
                acc[i][1] += xv.x * w0.y + xv.y * w1.y + xv.z * w2.y + xv.w * w3.y;
                acc[i][2] += xv.x * w0.z + xv.y * w1.z + xv.z * w2.z + xv.w * w3.z;
                acc[i][3] += xv.x * w0.w + xv.y * w1.w + xv.z * w2.w + xv.w * w3.w;
            }
        }
        __syncthreads();
    }
    #pragma unroll
    for (int i = 0; i < 8; ++i) {
        int gr = row0 + rg * 8 + i;
        if (gr < n) {
            float dv = dinv[gr];
            float4 o = make_float4(acc[i][0] * dv, acc[i][1] * dv,
                                   acc[i][2] * dv, acc[i][3] * dv);
            *(float4*)&HS[gr * 128 + cg * 4] = o;
        }
    }
}

// out[v] = lrelu( (hs[v]+sum_{incoming} hs[src]) * dinv[v] * A[j] + C[j] ) (+ res[v])
__global__ __launch_bounds__(256) void k_aggr(const float* __restrict__ hs,
                                              const int* __restrict__ rowptr,
                                              const int* __restrict__ csrc,
                                              const float* __restrict__ dinv,
                                              const float* __restrict__ A,
                                              const float* __restrict__ C,
                                              const float* __restrict__ res,
                                              float* __restrict__ xout, int n) {
    int node = blockIdx.x * 4 + (threadIdx.x >> 6);
    if (node >= n) return;
    int lane = threadIdx.x & 63;
    const float2* hs2 = (const float2*)hs;
    float2 acc = hs2[node * 64 + lane];   // self loop
    int e = rowptr[node], end = rowptr[node + 1];
    for (; e + 4 <= end; e += 4) {
        int s0 = csrc[e], s1 = csrc[e + 1], s2 = csrc[e + 2], s3 = csrc[e + 3];
        float2 t0 = hs2[s0 * 64 + lane];
        float2 t1 = hs2[s1 * 64 + lane];
        float2 t2 = hs2[s2 * 64 + lane];
        float2 t3 = hs2[s3 * 64 + lane];
        acc.x += t0.x + t1.x + t2.x + t3.x;
        acc.y += t0.y + t1.y + t2.y + t3.y;
    }
    for (; e < end; ++e) {
        int s = csrc[e];
        float2 t = hs2[s * 64 + lane];
        acc.x += t.x; acc.y += t.y;
    }
    float dv = dinv[node];
    float2 a2 = ((const float2*)A)[lane];
    float2 c2 = ((const float2*)C)[lane];
    float t0 = acc.x * dv * a2.x + c2.x;
    float t1 = acc.y * dv * a2.y + c2.y;
    t0 = (t0 >= 0.f) ? t0 : 0.01f * t0;
    t1 = (t1 >= 0.f) ? t1 : 0.01f * t1;
    if (res) {
        float2 r = ((const float2*)res)[node * 64 + lane];
        t0 += r.x; t1 += r.y;
    }
    ((float2*)xout)[node * 64 + lane] = make_float2(t0, t1);
}

// lb[g] = first index with batch[idx] >= g  (batch sorted ascending), g in [0,64]
__global__ void k_bounds(const int* __restrict__ batch, int n, int* __restrict__ lb) {
    int g = threadIdx.x;
    if (g > GDIM) return;
    int lo = 0, hi = n;
    while (lo < hi) {
        int mid = (lo + hi) >> 1;
        if (batch[mid] < g) lo = mid + 1; else hi = mid;
    }
    lb[g] = lo;
}

// chunked sorted-batch pooling: few atomics per block
__global__ __launch_bounds__(128) void k_pool(const float* __restrict__ x3,
                                              const int* __restrict__ batch,
                                              float* __restrict__ pool, int n) {
    int start = blockIdx.x * 256;
    int end = min(start + 256, n);
    int j = threadIdx.x;
    float acc = 0.f;
    int cur = batch[start];
    for (int v = start; v < end; ++v) {
        int g = batch[v];
        if (g != cur) {
            atomicAdd(&pool[cur * 128 + j], acc);
            acc = 0.f; cur = g;
        }
        acc += x3[(size_t)v * 128 + j];
    }
    atomicAdd(&pool[cur * 128 + j], acc);
}

__global__ __launch_bounds__(128) void k_head(const float* __restrict__ pool,
                                              const int* __restrict__ lb,
                                              const float* __restrict__ fcW1,
                                              const float* __restrict__ fcb1,
                                              const float* __restrict__ fcW2,
                                              const float* __restrict__ fcb2,
                                              float* __restrict__ out) {
    int g = blockIdx.x;
    int j = threadIdx.x;
    __shared__ float ph[128];
    __shared__ float hh[128];
    float cnt = (float)(lb[g + 1] - lb[g]);
    float inv = 1.0f / fmaxf(cnt, 1.0f);
    ph[j] = pool[g * 128 + j] * inv;
    __syncthreads();
    float a = fcb1[j];
    for (int k = 0; k < 128; ++k) a += ph[k] * fcW1[k * 128 + j];
    hh[j] = (a >= 0.f) ? a : 0.01f * a;
    __syncthreads();
    if (j < DDIM) {
        float o = fcb2[j];
        for (int k = 0; k < 128; ++k) o += hh[k] * fcW2[k * DDIM + j];
        float ss = o * o;
        #pragma unroll
        for (int off = 32; off > 0; off >>= 1) ss += __shfl_xor(ss, off);
        float nrm = sqrtf(ss);
        out[g * DDIM + j] = o / fmaxf(nrm, 1e-12f);
    }
}

extern "C" void kernel_launch(void* const* d_in, const int* in_sizes, int n_in,
                              void* d_out, int out_size, void* d_ws, size_t ws_size,
                              hipStream_t stream) {
    const float* x      = (const float*)d_in[0];
    const int*   ei     = (const int*)d_in[1];
    const int*   batch  = (const int*)d_in[2];
    const float* W1     = (const float*)d_in[3];
    const float* b1     = (const float*)d_in[4];
    const float* W2     = (const float*)d_in[5];
    const float* b2     = (const float*)d_in[6];
    const float* W3     = (const float*)d_in[7];
    const float* b3     = (const float*)d_in[8];
    const float* g1     = (const float*)d_in[9];
    const float* be1    = (const float*)d_in[10];
    const float* m1     = (const float*)d_in[11];
    const float* v1     = (const float*)d_in[12];
    const float* g2     = (const float*)d_in[13];
    const float* be2    = (const float*)d_in[14];
    const float* m2     = (const float*)d_in[15];
    const float* v2     = (const float*)d_in[16];
    const float* g3     = (const float*)d_in[17];
    const float* be3    = (const float*)d_in[18];
    const float* m3     = (const float*)d_in[19];
    const float* v3     = (const float*)d_in[20];
    const float* fcW1   = (const float*)d_in[21];
    const float* fcb1   = (const float*)d_in[22];
    const float* fcW2   = (const float*)d_in[23];
    const float* fcb2   = (const float*)d_in[24];
    float* out = (float*)d_out;

    const int N = in_sizes[0] / HDIM;       // 100000
    const int E = in_sizes[1] / 2;          // 1600000
    const int* srcp = ei;
    const int* dstp = ei + E;
    const int scanBlocks = (N + 1023) / 1024;   // 98

    // ---- workspace layout (512B aligned) ----
    char* base = (char*)d_ws;
    size_t off = 0;
    auto alloc = [&](size_t bytes) -> char* {
        char* p = base + off;
        off += (bytes + 511) & ~(size_t)511;
        return p;
    };
    int*   degcnt = (int*)  alloc((size_t)N * 4);
    int*   fill   = (int*)  alloc((size_t)N * 4);
    int*   rowptr = (int*)  alloc((size_t)(N + 4) * 4);
    int*   csrc   = (int*)  alloc((size_t)E * 4);
    float* dinv   = (float*)alloc((size_t)(N + 4) * 4);
    int*   bsum   = (int*)  alloc(128 * 4);
    int*   boff   = (int*)  alloc(128 * 4);
    float* AC     = (float*)alloc(3 * 256 * 4);
    int*   lb     = (int*)  alloc((GDIM + 1) * 4);
    float* pool   = (float*)alloc(GDIM * HDIM * 4);
    float* hs     = (float*)alloc((size_t)N * HDIM * 4);
    float* bufA   = (float*)alloc((size_t)N * HDIM * 4);
    float* bufB   = (float*)alloc((size_t)N * HDIM * 4);
    if (off > ws_size) return;  // workspace too small -> fail validation loudly

    // ---- zero-init counters/accumulators ----
    hipMemsetAsync(degcnt, 0, (size_t)N * 4, stream);
    hipMemsetAsync(fill,   0, (size_t)N * 4, stream);
    hipMemsetAsync(pool,   0, GDIM * HDIM * 4, stream);

    // ---- graph structure (once, reused by all 3 layers) ----
    k_bounds<<<1, 128, 0, stream>>>(batch, N, lb);
    k_count<<<(E + 255) / 256, 256, 0, stream>>>(dstp, E, degcnt);
    k_scan_a<<<scanBlocks, 256, 0, stream>>>(degcnt, bsum, dinv, N);
    k_scan_b<<<1, 128, 0, stream>>>(bsum, scanBlocks, boff, rowptr, N);
    k_scan_c<<<scanBlocks, 256, 0, stream>>>(degcnt, boff, rowptr, N);
    k_fill<<<(E + 255) / 256, 256, 0, stream>>>(srcp, dstp, E, rowptr, fill, csrc);

    // ---- fold bias+BN(eval) into per-channel A,C ----
    k_bnprep<<<3, 128, 0, stream>>>(b1, g1, be1, m1, v1, b2, g2, be2, m2, v2,
                                    b3, g3, be3, m3, v3, AC);

    int gemmBlocks = (N + 127) / 128;
    int aggrBlocks = (N + 3) / 4;

    // layer 1: x -> bufA
    k_gemm_scale<<<gemmBlocks, 512, 0, stream>>>(x, W1, dinv, hs, N);
    k_aggr<<<aggrBlocks, 256, 0, stream>>>(hs, rowptr, csrc, dinv,
                                           AC + 0 * 256, AC + 0 * 256 + 128,
                                           nullptr, bufA, N);
    // layer 2: bufA -> bufB (+bufA residual)
    k_gemm_scale<<<gemmBlocks, 512, 0, stream>>>(bufA, W2, dinv, hs, N);
    k_aggr<<<aggrBlocks, 256, 0, stream>>>(hs, rowptr, csrc, dinv,
                                           AC + 1 * 256, AC + 1 * 256 + 128,
                                           bufA, bufB, N);
    // layer 3: bufB -> bufA (+bufB residual)
    k_gemm_scale<<<gemmBlocks, 512, 0, stream>>>(bufB, W3, dinv, hs, N);
    k_aggr<<<aggrBlocks, 256, 0, stream>>>(hs, rowptr, csrc, dinv,
                                           AC + 2 * 256, AC + 2 * 256 + 128,
                                           bufB, bufA, N);

    // ---- pool + head ----
    k_pool<<<(N + 255) / 256, 128, 0, stream>>>(bufA, batch, pool, N);
    k_head<<<GDIM, 128, 0, stream>>>(pool, lb, fcW1, fcb1, fcW2, fcb2, out);
}

// Round 7
// 916.891 us; speedup vs baseline: 3.0763x; 2.2601x over previous
//
#include <hip/hip_runtime.h>
#include <hip/hip_bf16.h>

// ImprovedGNN: 3x GCNConv(+BN eval+LeakyReLU+residual) -> mean-pool -> MLP -> L2 norm
//  - deg/dinv computed ONCE; CSR built once; per layer: GEMM (dinv-fused) + gather
//  - R1: launch_bounds(512,4) -> VGPR cap 64 -> massive spill (1.8GB/dispatch).
//  - R5: (512,2) -> VGPR 128, STILL spilling (WRITE 718MB vs 51MB ideal, VALUBusy
//    7.7%): 8x4 blocking needs ~140 live regs. Fix: 4x4 blocking (BM=64, 512thr,
//    acc 16 + W 16 + xv 16 ~= 70 live), LDS 48KB -> 3 blocks/CU, unroll-4 k-loop.
//  - R6: infra timeout, never measured. Resubmitting unchanged.

#define HDIM  128
#define GDIM  64
#define DDIM  64

__global__ void k_count(const int* __restrict__ dst, int e, int* __restrict__ cnt) {
    int i = blockIdx.x * blockDim.x + threadIdx.x;
    if (i < e) atomicAdd(&cnt[dst[i]], 1);
}

// ---- 3-phase exclusive scan of cnt -> rowptr, dinv folded into phase A ----
__global__ __launch_bounds__(256) void k_scan_a(const int* __restrict__ cnt,
                                                int* __restrict__ bsum,
                                                float* __restrict__ dinv, int n) {
    int b = blockIdx.x, t = threadIdx.x;
    int i4 = b * 256 + t, base = i4 * 4;
    int4 v = make_int4(0, 0, 0, 0);
    if (base + 3 < n) {
        v = ((const int4*)cnt)[i4];
        float4 dv = make_float4(rsqrtf((float)v.x + 1.f), rsqrtf((float)v.y + 1.f),
                                rsqrtf((float)v.z + 1.f), rsqrtf((float)v.w + 1.f));
        ((float4*)dinv)[i4] = dv;
    } else {
        if (base + 0 < n) { v.x = cnt[base + 0]; dinv[base + 0] = rsqrtf((float)v.x + 1.f); }
        if (base + 1 < n) { v.y = cnt[base + 1]; dinv[base + 1] = rsqrtf((float)v.y + 1.f); }
        if (base + 2 < n) { v.z = cnt[base + 2]; dinv[base + 2] = rsqrtf((float)v.z + 1.f); }
        if (base + 3 < n) { v.w = cnt[base + 3]; dinv[base + 3] = rsqrtf((float)v.w + 1.f); }
    }
    __shared__ int red[256];
    red[t] = v.x + v.y + v.z + v.w;
    __syncthreads();
    #pragma unroll
    for (int off = 128; off > 0; off >>= 1) {
        if (t < off) red[t] += red[t + off];
        __syncthreads();
    }
    if (t == 0) bsum[b] = red[0];
}

__global__ __launch_bounds__(128) void k_scan_b(const int* __restrict__ bsum, int nb,
                                                int* __restrict__ boff,
                                                int* __restrict__ rowptr, int n) {
    __shared__ int sh[128];
    int t = threadIdx.x;
    int v = (t < nb) ? bsum[t] : 0;
    sh[t] = v;
    __syncthreads();
    #pragma unroll
    for (int off = 1; off < 128; off <<= 1) {
        int u = (t >= off) ? sh[t - off] : 0;
        __syncthreads();
        sh[t] += u;
        __syncthreads();
    }
    boff[t] = sh[t] - v;
    if (t == 127) rowptr[n] = sh[127];
}

__global__ __launch_bounds__(256) void k_scan_c(const int* __restrict__ cnt,
                                                const int* __restrict__ boff,
                                                int* __restrict__ rowptr, int n) {
    int b = blockIdx.x, t = threadIdx.x;
    int i4 = b * 256 + t, base = i4 * 4;
    int4 v = make_int4(0, 0, 0, 0);
    if (base + 3 < n) v = ((const int4*)cnt)[i4];
    else {
        if (base + 0 < n) v.x = cnt[base + 0];
        if (base + 1 < n) v.y = cnt[base + 1];
        if (base + 2 < n) v.z = cnt[base + 2];
        if (base + 3 < n) v.w = cnt[base + 3];
    }
    int s = v.x + v.y + v.z + v.w;
    __shared__ int sh[256];
    sh[t] = s;
    __syncthreads();
    #pragma unroll
    for (int off = 1; off < 256; off <<= 1) {
        int u = (t >= off) ? sh[t - off] : 0;
        __syncthreads();
        sh[t] += u;
        __syncthreads();
    }
    int excl = sh[t] - s + boff[b];
    if (base + 3 < n) {
        ((int4*)rowptr)[i4] = make_int4(excl, excl + v.x, excl + v.x + v.y,
                                        excl + v.x + v.y + v.z);
    } else {
        if (base + 0 < n) rowptr[base + 0] = excl;
        if (base + 1 < n) rowptr[base + 1] = excl + v.x;
        if (base + 2 < n) rowptr[base + 2] = excl + v.x + v.y;
        if (base + 3 < n) rowptr[base + 3] = excl + v.x + v.y + v.z;
    }
}

__global__ void k_fill(const int* __restrict__ src, const int* __restrict__ dst, int e,
                       const int* __restrict__ rowptr, int* __restrict__ fill,
                       int* __restrict__ csrc) {
    int i = blockIdx.x * blockDim.x + threadIdx.x;
    if (i < e) {
        int d = dst[i];
        int pos = rowptr[d] + atomicAdd(&fill[d], 1);
        csrc[pos] = src[i];
    }
}

// fold bias+BN(eval) into per-channel A,C for all 3 layers (block l = layer l)
__global__ void k_bnprep(const float* __restrict__ b1, const float* __restrict__ g1,
                         const float* __restrict__ be1, const float* __restrict__ m1,
                         const float* __restrict__ v1,
                         const float* __restrict__ b2, const float* __restrict__ g2,
                         const float* __restrict__ be2, const float* __restrict__ m2,
                         const float* __restrict__ v2,
                         const float* __restrict__ b3, const float* __restrict__ g3,
                         const float* __restrict__ be3, const float* __restrict__ m3,
                         const float* __restrict__ v3,
                         float* __restrict__ AC) {
    int l = blockIdx.x, j = threadIdx.x;
    const float* b  = (l == 0) ? b1  : (l == 1) ? b2  : b3;
    const float* g  = (l == 0) ? g1  : (l == 1) ? g2  : g3;
    const float* be = (l == 0) ? be1 : (l == 1) ? be2 : be3;
    const float* m  = (l == 0) ? m1  : (l == 1) ? m2  : m3;
    const float* v  = (l == 0) ? v1  : (l == 1) ? v2  : v3;
    float sc = g[j] * rsqrtf(v[j] + 1e-5f);
    AC[l * 256 + j] = sc;
    AC[l * 256 + 128 + j] = (b[j] - m[j]) * sc + be[j];
}

// hs[r][:] = (X[r][:] @ W) * dinv[r].   X:[n,128] W:[128,128]
// BM=64 rows/block, 512 threads, BK=64 (2 k-tiles), 4x4 register blocking.
// Live regs ~70 (acc 16 + W 16 + xv <=16 + addr) -> no spill at any occupancy.
__global__ __launch_bounds__(512, 2) void k_gemm_scale(const float* __restrict__ X,
                                                       const float* __restrict__ W,
                                                       const float* __restrict__ dinv,
                                                       float* __restrict__ HS, int n) {
    __shared__ float ws[64 * 128];   // W[kk][j]  32KB
    __shared__ float xs[64 * 64];    // x[r][kk]  16KB
    int tid = threadIdx.x;
    int row0 = blockIdx.x * 64;
    int cg = tid & 31;    // cols 4*cg..4*cg+3
    int rg = tid >> 5;    // rows rg*4..rg*4+3 (rg 0..15)
    float acc[4][4] = {};
    const float4* X4 = (const float4*)X;
    const float4* W4 = (const float4*)W;
    float4* ws4 = (float4*)ws;
    float4* xs4 = (float4*)xs;
    for (int kt = 0; kt < 2; ++kt) {
        // stage W rows [kt*64, +64): 2048 float4, 4/thread
        #pragma unroll
        for (int t = 0; t < 4; ++t) {
            int idx = tid + t * 512;
            int r = idx >> 5, c = idx & 31;
            ws4[idx] = W4[(kt * 64 + r) * 32 + c];
        }
        // stage X tile [row0..row0+64) x [kt*64, +64): 1024 float4, 2/thread
        #pragma unroll
        for (int t = 0; t < 2; ++t) {
            int idx = tid + t * 512;
            int r = idx >> 4, c4 = idx & 15;
            int gr = row0 + r;
            xs4[idx] = (gr < n) ? X4[gr * 32 + kt * 16 + c4] : make_float4(0.f, 0.f, 0.f, 0.f);
        }
        __syncthreads();
        #pragma unroll 4
        for (int k4 = 0; k4 < 16; ++k4) {
            float4 w0 = *(const float4*)&ws[(k4 * 4 + 0) * 128 + cg * 4];
            float4 w1 = *(const float4*)&ws[(k4 * 4 + 1) * 128 + cg * 4];
            float4 w2 = *(const float4*)&ws[(k4 * 4 + 2) * 128 + cg * 4];
            float4 w3 = *(const float4*)&ws[(k4 * 4 + 3) * 128 + cg * 4];
            #pragma unroll
            for (int i = 0; i < 4; ++i) {
                float4 xv = *(const float4*)&xs[(rg * 4 + i) * 64 + k4 * 4];
                acc[i][0] += xv.x * w0.x + xv.y * w1.x + xv.z * w2.x + xv.w * w3.x;
                acc[i][1] += xv.x * w0.y + xv.y * w1.y + xv.z * w2.y + xv.w * w3.y;
                acc[i][2] += xv.x * w0.z + xv.y * w1.z + xv.z * w2.z + xv.w * w3.z;
                acc[i][3] += xv.x * w0.w + xv.y * w1.w + xv.z * w2.w + xv.w * w3.w;
            }
        }
        __syncthreads();
    }
    #pragma unroll
    for (int i = 0; i < 4; ++i) {
        int gr = row0 + rg * 4 + i;
        if (gr < n) {
            float dv = dinv[gr];
            float4 o = make_float4(acc[i][0] * dv, acc[i][1] * dv,
                                   acc[i][2] * dv, acc[i][3] * dv);
            *(float4*)&HS[gr * 128 + cg * 4] = o;
        }
    }
}

// out[v] = lrelu( (hs[v]+sum_{incoming} hs[src]) * dinv[v] * A[j] + C[j] ) (+ res[v])
__global__ __launch_bounds__(256) void k_aggr(const float* __restrict__ hs,
                                              const int* __restrict__ rowptr,
                                              const int* __restrict__ csrc,
                                              const float* __restrict__ dinv,
                                              const float* __restrict__ A,
                                              const float* __restrict__ C,
                                              const float* __restrict__ res,
                                              float* __restrict__ xout, int n) {
    int node = blockIdx.x * 4 + (threadIdx.x >> 6);
    if (node >= n) return;
    int lane = threadIdx.x & 63;
    const float2* hs2 = (const float2*)hs;
    float2 acc = hs2[node * 64 + lane];   // self loop
    int e = rowptr[node], end = rowptr[node + 1];
    for (; e + 4 <= end; e += 4) {
        int s0 = csrc[e], s1 = csrc[e + 1], s2 = csrc[e + 2], s3 = csrc[e + 3];
        float2 t0 = hs2[s0 * 64 + lane];
        float2 t1 = hs2[s1 * 64 + lane];
        float2 t2 = hs2[s2 * 64 + lane];
        float2 t3 = hs2[s3 * 64 + lane];
        acc.x += t0.x + t1.x + t2.x + t3.x;
        acc.y += t0.y + t1.y + t2.y + t3.y;
    }
    for (; e < end; ++e) {
        int s = csrc[e];
        float2 t = hs2[s * 64 + lane];
        acc.x += t.x; acc.y += t.y;
    }
    float dv = dinv[node];
    float2 a2 = ((const float2*)A)[lane];
    float2 c2 = ((const float2*)C)[lane];
    float t0 = acc.x * dv * a2.x + c2.x;
    float t1 = acc.y * dv * a2.y + c2.y;
    t0 = (t0 >= 0.f) ? t0 : 0.01f * t0;
    t1 = (t1 >= 0.f) ? t1 : 0.01f * t1;
    if (res) {
        float2 r = ((const float2*)res)[node * 64 + lane];
        t0 += r.x; t1 += r.y;
    }
    ((float2*)xout)[node * 64 + lane] = make_float2(t0, t1);
}

// lb[g] = first index with batch[idx] >= g  (batch sorted ascending), g in [0,64]
__global__ void k_bounds(const int* __restrict__ batch, int n, int* __restrict__ lb) {
    int g = threadIdx.x;
    if (g > GDIM) return;
    int lo = 0, hi = n;
    while (lo < hi) {
        int mid = (lo + hi) >> 1;
        if (batch[mid] < g) lo = mid + 1; else hi = mid;
    }
    lb[g] = lo;
}

// chunked sorted-batch pooling: few atomics per block
__global__ __launch_bounds__(128) void k_pool(const float* __restrict__ x3,
                                              const int* __restrict__ batch,
                                              float* __restrict__ pool, int n) {
    int start = blockIdx.x * 256;
    int end = min(start + 256, n);
    int j = threadIdx.x;
    float acc = 0.f;
    int cur = batch[start];
    for (int v = start; v < end; ++v) {
        int g = batch[v];
        if (g != cur) {
            atomicAdd(&pool[cur * 128 + j], acc);
            acc = 0.f; cur = g;
        }
        acc += x3[(size_t)v * 128 + j];
    }
    atomicAdd(&pool[cur * 128 + j], acc);
}

__global__ __launch_bounds__(128) void k_head(const float* __restrict__ pool,
                                              const int* __restrict__ lb,
                                              const float* __restrict__ fcW1,
                                              const float* __restrict__ fcb1,
                                              const float* __restrict__ fcW2,
                                              const float* __restrict__ fcb2,
                                              float* __restrict__ out) {
    int g = blockIdx.x;
    int j = threadIdx.x;
    __shared__ float ph[128];
    __shared__ float hh[128];
    float cnt = (float)(lb[g + 1] - lb[g]);
    float inv = 1.0f / fmaxf(cnt, 1.0f);
    ph[j] = pool[g * 128 + j] * inv;
    __syncthreads();
    float a = fcb1[j];
    for (int k = 0; k < 128; ++k) a += ph[k] * fcW1[k * 128 + j];
    hh[j] = (a >= 0.f) ? a : 0.01f * a;
    __syncthreads();
    if (j < DDIM) {
        float o = fcb2[j];
        for (int k = 0; k < 128; ++k) o += hh[k] * fcW2[k * DDIM + j];
        float ss = o * o;
        #pragma unroll
        for (int off = 32; off > 0; off >>= 1) ss += __shfl_xor(ss, off);
        float nrm = sqrtf(ss);
        out[g * DDIM + j] = o / fmaxf(nrm, 1e-12f);
    }
}

extern "C" void kernel_launch(void* const* d_in, const int* in_sizes, int n_in,
                              void* d_out, int out_size, void* d_ws, size_t ws_size,
                              hipStream_t stream) {
    const float* x      = (const float*)d_in[0];
    const int*   ei     = (const int*)d_in[1];
    const int*   batch  = (const int*)d_in[2];
    const float* W1     = (const float*)d_in[3];
    const float* b1     = (const float*)d_in[4];
    const float* W2     = (const float*)d_in[5];
    const float* b2     = (const float*)d_in[6];
    const float* W3     = (const float*)d_in[7];
    const float* b3     = (const float*)d_in[8];
    const float* g1     = (const float*)d_in[9];
    const float* be1    = (const float*)d_in[10];
    const float* m1     = (const float*)d_in[11];
    const float* v1     = (const float*)d_in[12];
    const float* g2     = (const float*)d_in[13];
    const float* be2    = (const float*)d_in[14];
    const float* m2     = (const float*)d_in[15];
    const float* v2     = (const float*)d_in[16];
    const float* g3     = (const float*)d_in[17];
    const float* be3    = (const float*)d_in[18];
    const float* m3     = (const float*)d_in[19];
    const float* v3     = (const float*)d_in[20];
    const float* fcW1   = (const float*)d_in[21];
    const float* fcb1   = (const float*)d_in[22];
    const float* fcW2   = (const float*)d_in[23];
    const float* fcb2   = (const float*)d_in[24];
    float* out = (float*)d_out;

    const int N = in_sizes[0] / HDIM;       // 100000
    const int E = in_sizes[1] / 2;          // 1600000
    const int* srcp = ei;
    const int* dstp = ei + E;
    const int scanBlocks = (N + 1023) / 1024;   // 98

    // ---- workspace layout (512B aligned) ----
    char* base = (char*)d_ws;
    size_t off = 0;
    auto alloc = [&](size_t bytes) -> char* {
        char* p = base + off;
        off += (bytes + 511) & ~(size_t)511;
        return p;
    };
    int*   degcnt = (int*)  alloc((size_t)N * 4);
    int*   fill   = (int*)  alloc((size_t)N * 4);
    int*   rowptr = (int*)  alloc((size_t)(N + 4) * 4);
    int*   csrc   = (int*)  alloc((size_t)E * 4);
    float* dinv   = (float*)alloc((size_t)(N + 4) * 4);
    int*   bsum   = (int*)  alloc(128 * 4);
    int*   boff   = (int*)  alloc(128 * 4);
    float* AC     = (float*)alloc(3 * 256 * 4);
    int*   lb     = (int*)  alloc((GDIM + 1) * 4);
    float* pool   = (float*)alloc(GDIM * HDIM * 4);
    float* hs     = (float*)alloc((size_t)N * HDIM * 4);
    float* bufA   = (float*)alloc((size_t)N * HDIM * 4);
    float* bufB   = (float*)alloc((size_t)N * HDIM * 4);
    if (off > ws_size) return;  // workspace too small -> fail validation loudly

    // ---- zero-init counters/accumulators ----
    hipMemsetAsync(degcnt, 0, (size_t)N * 4, stream);
    hipMemsetAsync(fill,   0, (size_t)N * 4, stream);
    hipMemsetAsync(pool,   0, GDIM * HDIM * 4, stream);

    // ---- graph structure (once, reused by all 3 layers) ----
    k_bounds<<<1, 128, 0, stream>>>(batch, N, lb);
    k_count<<<(E + 255) / 256, 256, 0, stream>>>(dstp, E, degcnt);
    k_scan_a<<<scanBlocks, 256, 0, stream>>>(degcnt, bsum, dinv, N);
    k_scan_b<<<1, 128, 0, stream>>>(bsum, scanBlocks, boff, rowptr, N);
    k_scan_c<<<scanBlocks, 256, 0, stream>>>(degcnt, boff, rowptr, N);
    k_fill<<<(E + 255) / 256, 256, 0, stream>>>(srcp, dstp, E, rowptr, fill, csrc);

    // ---- fold bias+BN(eval) into per-channel A,C ----
    k_bnprep<<<3, 128, 0, stream>>>(b1, g1, be1, m1, v1, b2, g2, be2, m2, v2,
                                    b3, g3, be3, m3, v3, AC);

    int gemmBlocks = (N + 63) / 64;
    int aggrBlocks = (N + 3) / 4;

    // layer 1: x -> bufA
    k_gemm_scale<<<gemmBlocks, 512, 0, stream>>>(x, W1, dinv, hs, N);
    k_aggr<<<aggrBlocks, 256, 0, stream>>>(hs, rowptr, csrc, dinv,
                                           AC + 0 * 256, AC + 0 * 256 + 128,
                                           nullptr, bufA, N);
    // layer 2: bufA -> bufB (+bufA residual)
    k_gemm_scale<<<gemmBlocks, 512, 0, stream>>>(bufA, W2, dinv, hs, N);
    k_aggr<<<aggrBlocks, 256, 0, stream>>>(hs, rowptr, csrc, dinv,
                                           AC + 1 * 256, AC + 1 * 256 + 128,
                                           bufA, bufB, N);
    // layer 3: bufB -> bufA (+bufB residual)
    k_gemm_scale<<<gemmBlocks, 512, 0, stream>>>(bufB, W3, dinv, hs, N);
    k_aggr<<<aggrBlocks, 256, 0, stream>>>(hs, rowptr, csrc, dinv,
                                           AC + 2 * 256, AC + 2 * 256 + 128,
                                           bufB, bufA, N);

    // ---- pool + head ----
    k_pool<<<(N + 255) / 256, 128, 0, stream>>>(bufA, batch, pool, N);
    k_head<<<GDIM, 128, 0, stream>>>(pool, lb, fcW1, fcb1, fcW2, fcb2, out);
}

// Round 10
// 911.843 us; speedup vs baseline: 3.0933x; 1.0055x over previous
//
#include <hip/hip_runtime.h>
#include <hip/hip_bf16.h>

// ImprovedGNN: 3x GCNConv(+BN eval+LeakyReLU+residual) -> mean-pool -> MLP -> L2 norm
//  - deg/dinv ONCE; CSR once; per layer: GEMM (dinv-fused) + CSR gather
//  - R1/R5: GEMM spill fixed via 4x4 blocking (R7: GEMM out of top-5, aggr leads)
//  - R7: k_aggr latency-bound (VALUBusy 16%, 3.8 TB/s eff, occ 77%). Fix: float4
//    per lane (32 lanes/row, 2 edges/wave/instr), 8-edge unroll, 2 accumulators,
//    __shfl_xor(32) cross-half combine. GEMM untouched for attribution.
//  - R8/R9: infra timeouts, never measured. Resubmitting unchanged.

#define HDIM  128
#define GDIM  64
#define DDIM  64

__global__ void k_count(const int* __restrict__ dst, int e, int* __restrict__ cnt) {
    int i = blockIdx.x * blockDim.x + threadIdx.x;
    if (i < e) atomicAdd(&cnt[dst[i]], 1);
}

// ---- 3-phase exclusive scan of cnt -> rowptr, dinv folded into phase A ----
__global__ __launch_bounds__(256) void k_scan_a(const int* __restrict__ cnt,
                                                int* __restrict__ bsum,
                                                float* __restrict__ dinv, int n) {
    int b = blockIdx.x, t = threadIdx.x;
    int i4 = b * 256 + t, base = i4 * 4;
    int4 v = make_int4(0, 0, 0, 0);
    if (base + 3 < n) {
        v = ((const int4*)cnt)[i4];
        float4 dv = make_float4(rsqrtf((float)v.x + 1.f), rsqrtf((float)v.y + 1.f),
                                rsqrtf((float)v.z + 1.f), rsqrtf((float)v.w + 1.f));
        ((float4*)dinv)[i4] = dv;
    } else {
        if (base + 0 < n) { v.x = cnt[base + 0]; dinv[base + 0] = rsqrtf((float)v.x + 1.f); }
        if (base + 1 < n) { v.y = cnt[base + 1]; dinv[base + 1] = rsqrtf((float)v.y + 1.f); }
        if (base + 2 < n) { v.z = cnt[base + 2]; dinv[base + 2] = rsqrtf((float)v.z + 1.f); }
        if (base + 3 < n) { v.w = cnt[base + 3]; dinv[base + 3] = rsqrtf((float)v.w + 1.f); }
    }
    __shared__ int red[256];
    red[t] = v.x + v.y + v.z + v.w;
    __syncthreads();
    #pragma unroll
    for (int off = 128; off > 0; off >>= 1) {
        if (t < off) red[t] += red[t + off];
        __syncthreads();
    }
    if (t == 0) bsum[b] = red[0];
}

__global__ __launch_bounds__(128) void k_scan_b(const int* __restrict__ bsum, int nb,
                                                int* __restrict__ boff,
                                                int* __restrict__ rowptr, int n) {
    __shared__ int sh[128];
    int t = threadIdx.x;
    int v = (t < nb) ? bsum[t] : 0;
    sh[t] = v;
    __syncthreads();
    #pragma unroll
    for (int off = 1; off < 128; off <<= 1) {
        int u = (t >= off) ? sh[t - off] : 0;
        __syncthreads();
        sh[t] += u;
        __syncthreads();
    }
    boff[t] = sh[t] - v;
    if (t == 127) rowptr[n] = sh[127];
}

__global__ __launch_bounds__(256) void k_scan_c(const int* __restrict__ cnt,
                                                const int* __restrict__ boff,
                                                int* __restrict__ rowptr, int n) {
    int b = blockIdx.x, t = threadIdx.x;
    int i4 = b * 256 + t, base = i4 * 4;
    int4 v = make_int4(0, 0, 0, 0);
    if (base + 3 < n) v = ((const int4*)cnt)[i4];
    else {
        if (base + 0 < n) v.x = cnt[base + 0];
        if (base + 1 < n) v.y = cnt[base + 1];
        if (base + 2 < n) v.z = cnt[base + 2];
        if (base + 3 < n) v.w = cnt[base + 3];
    }
    int s = v.x + v.y + v.z + v.w;
    __shared__ int sh[256];
    sh[t] = s;
    __syncthreads();
    #pragma unroll
    for (int off = 1; off < 256; off <<= 1) {
        int u = (t >= off) ? sh[t - off] : 0;
        __syncthreads();
        sh[t] += u;
        __syncthreads();
    }
    int excl = sh[t] - s + boff[b];
    if (base + 3 < n) {
        ((int4*)rowptr)[i4] = make_int4(excl, excl + v.x, excl + v.x + v.y,
                                        excl + v.x + v.y + v.z);
    } else {
        if (base + 0 < n) rowptr[base + 0] = excl;
        if (base + 1 < n) rowptr[base + 1] = excl + v.x;
        if (base + 2 < n) rowptr[base + 2] = excl + v.x + v.y;
        if (base + 3 < n) rowptr[base + 3] = excl + v.x + v.y + v.z;
    }
}

__global__ void k_fill(const int* __restrict__ src, const int* __restrict__ dst, int e,
                       const int* __restrict__ rowptr, int* __restrict__ fill,
                       int* __restrict__ csrc) {
    int i = blockIdx.x * blockDim.x + threadIdx.x;
    if (i < e) {
        int d = dst[i];
        int pos = rowptr[d] + atomicAdd(&fill[d], 1);
        csrc[pos] = src[i];
    }
}

// fold bias+BN(eval) into per-channel A,C for all 3 layers (block l = layer l)
__global__ void k_bnprep(const float* __restrict__ b1, const float* __restrict__ g1,
                         const float* __restrict__ be1, const float* __restrict__ m1,
                         const float* __restrict__ v1,
                         const float* __restrict__ b2, const float* __restrict__ g2,
                         const float* __restrict__ be2, const float* __restrict__ m2,
                         const float* __restrict__ v2,
                         const float* __restrict__ b3, const float* __restrict__ g3,
                         const float* __restrict__ be3, const float* __restrict__ m3,
                         const float* __restrict__ v3,
                         float* __restrict__ AC) {
    int l = blockIdx.x, j = threadIdx.x;
    const float* b  = (l == 0) ? b1  : (l == 1) ? b2  : b3;
    const float* g  = (l == 0) ? g1  : (l == 1) ? g2  : g3;
    const float* be = (l == 0) ? be1 : (l == 1) ? be2 : be3;
    const float* m  = (l == 0) ? m1  : (l == 1) ? m2  : m3;
    const float* v  = (l == 0) ? v1  : (l == 1) ? v2  : v3;
    float sc = g[j] * rsqrtf(v[j] + 1e-5f);
    AC[l * 256 + j] = sc;
    AC[l * 256 + 128 + j] = (b[j] - m[j]) * sc + be[j];
}

// hs[r][:] = (X[r][:] @ W) * dinv[r].   X:[n,128] W:[128,128]
// BM=64 rows/block, 512 threads, BK=64 (2 k-tiles), 4x4 register blocking.
__global__ __launch_bounds__(512, 2) void k_gemm_scale(const float* __restrict__ X,
                                                       const float* __restrict__ W,
                                                       const float* __restrict__ dinv,
                                                       float* __restrict__ HS, int n) {
    __shared__ float ws[64 * 128];   // W[kk][j]  32KB
    __shared__ float xs[64 * 64];    // x[r][kk]  16KB
    int tid = threadIdx.x;
    int row0 = blockIdx.x * 64;
    int cg = tid & 31;    // cols 4*cg..4*cg+3
    int rg = tid >> 5;    // rows rg*4..rg*4+3 (rg 0..15)
    float acc[4][4] = {};
    const float4* X4 = (const float4*)X;
    const float4* W4 = (const float4*)W;
    float4* ws4 = (float4*)ws;
    float4* xs4 = (float4*)xs;
    for (int kt = 0; kt < 2; ++kt) {
        #pragma unroll
        for (int t = 0; t < 4; ++t) {
            int idx = tid + t * 512;
            int r = idx >> 5, c = idx & 31;
            ws4[idx] = W4[(kt * 64 + r) * 32 + c];
        }
        #pragma unroll
        for (int t = 0; t < 2; ++t) {
            int idx = tid + t * 512;
            int r = idx >> 4, c4 = idx & 15;
            int gr = row0 + r;
            xs4[idx] = (gr < n) ? X4[gr * 32 + kt * 16 + c4] : make_float4(0.f, 0.f, 0.f, 0.f);
        }
        __syncthreads();
        #pragma unroll 4
        for (int k4 = 0; k4 < 16; ++k4) {
            float4 w0 = *(const float4*)&ws[(k4 * 4 + 0) * 128 + cg * 4];
            float4 w1 = *(const float4*)&ws[(k4 * 4 + 1) * 128 + cg * 4];
            float4 w2 = *(const float4*)&ws[(k4 * 4 + 2) * 128 + cg * 4];
            float4 w3 = *(const float4*)&ws[(k4 * 4 + 3) * 128 + cg * 4];
            #pragma unroll
            for (int i = 0; i < 4; ++i) {
                float4 xv = *(const float4*)&xs[(rg * 4 + i) * 64 + k4 * 4];
                acc[i][0] += xv.x * w0.x + xv.y * w1.x + xv.z * w2.x + xv.w * w3.x;
                acc[i][1] += xv.x * w0.y + xv.y * w1.y + xv.z * w2.y + xv.w * w3.y;
                acc[i][2] += xv.x * w0.z + xv.y * w1.z + xv.z * w2.z + xv.w * w3.z;
                acc[i][3] += xv.x * w0.w + xv.y * w1.w + xv.z * w2.w + xv.w * w3.w;
            }
        }
        __syncthreads();
    }
    #pragma unroll
    for (int i = 0; i < 4; ++i) {
        int gr = row0 + rg * 4 + i;
        if (gr < n) {
            float dv = dinv[gr];
            float4 o = make_float4(acc[i][0] * dv, acc[i][1] * dv,
                                   acc[i][2] * dv, acc[i][3] * dv);
            *(float4*)&HS[gr * 128 + cg * 4] = o;
        }
    }
}

// out[v] = lrelu( (hs[v]+sum_{in} hs[src]) * dinv[v] * A[j] + C[j] ) (+ res[v])
// One wave per node. float4 per lane: 32 lanes cover a 512B row; the two wave
// halves process edges e+0 / e+1 -> 2 edges per load instr, 8 edges per iter.
__global__ __launch_bounds__(256) void k_aggr(const float* __restrict__ hs,
                                              const int* __restrict__ rowptr,
                                              const int* __restrict__ csrc,
                                              const float* __restrict__ dinv,
                                              const float* __restrict__ A,
                                              const float* __restrict__ C,
                                              const float* __restrict__ res,
                                              float* __restrict__ xout, int n) {
    int node = blockIdx.x * 4 + (threadIdx.x >> 6);
    if (node >= n) return;
    int lane = threadIdx.x & 63;
    int half = lane >> 5;        // 0: even edges, 1: odd edges
    int c    = lane & 31;        // float4 channel group
    const float4* hs4 = (const float4*)hs;

    float4 a0 = make_float4(0.f, 0.f, 0.f, 0.f);   // half 0 seeds with self-loop
    float4 a1 = make_float4(0.f, 0.f, 0.f, 0.f);
    if (half == 0) a0 = hs4[node * 32 + c];

    int e = rowptr[node], end = rowptr[node + 1];
    for (; e + 8 <= end; e += 8) {
        int s0 = csrc[e + 0 + half];
        int s1 = csrc[e + 2 + half];
        int s2 = csrc[e + 4 + half];
        int s3 = csrc[e + 6 + half];
        float4 t0 = hs4[s0 * 32 + c];
        float4 t1 = hs4[s1 * 32 + c];
        float4 t2 = hs4[s2 * 32 + c];
        float4 t3 = hs4[s3 * 32 + c];
        a0.x += t0.x + t1.x; a0.y += t0.y + t1.y; a0.z += t0.z + t1.z; a0.w += t0.w + t1.w;
        a1.x += t2.x + t3.x; a1.y += t2.y + t3.y; a1.z += t2.z + t3.z; a1.w += t2.w + t3.w;
    }
    for (; e + 2 <= end; e += 2) {
        int s = csrc[e + half];
        float4 t = hs4[s * 32 + c];
        a0.x += t.x; a0.y += t.y; a0.z += t.z; a0.w += t.w;
    }
    if (e < end && half == 0) {          // odd leftover edge: half 0 only
        int s = csrc[e];
        float4 t = hs4[s * 32 + c];
        a0.x += t.x; a0.y += t.y; a0.z += t.z; a0.w += t.w;
    }
    float4 acc = make_float4(a0.x + a1.x, a0.y + a1.y, a0.z + a1.z, a0.w + a1.w);
    // combine the two halves: lane j gets lane j^32's partial
    acc.x += __shfl_xor(acc.x, 32);
    acc.y += __shfl_xor(acc.y, 32);
    acc.z += __shfl_xor(acc.z, 32);
    acc.w += __shfl_xor(acc.w, 32);

    if (half == 0) {
        float dv = dinv[node];
        float4 a4 = ((const float4*)A)[c];
        float4 c4 = ((const float4*)C)[c];
        float t0 = acc.x * dv * a4.x + c4.x;
        float t1 = acc.y * dv * a4.y + c4.y;
        float t2 = acc.z * dv * a4.z + c4.z;
        float t3 = acc.w * dv * a4.w + c4.w;
        t0 = (t0 >= 0.f) ? t0 : 0.01f * t0;
        t1 = (t1 >= 0.f) ? t1 : 0.01f * t1;
        t2 = (t2 >= 0.f) ? t2 : 0.01f * t2;
        t3 = (t3 >= 0.f) ? t3 : 0.01f * t3;
        if (res) {
            float4 r = ((const float4*)res)[node * 32 + c];
            t0 += r.x; t1 += r.y; t2 += r.z; t3 += r.w;
        }
        ((float4*)xout)[node * 32 + c] = make_float4(t0, t1, t2, t3);
    }
}

// lb[g] = first index with batch[idx] >= g  (batch sorted ascending), g in [0,64]
__global__ void k_bounds(const int* __restrict__ batch, int n, int* __restrict__ lb) {
    int g = threadIdx.x;
    if (g > GDIM) return;
    int lo = 0, hi = n;
    while (lo < hi) {
        int mid = (lo + hi) >> 1;
        if (batch[mid] < g) lo = mid + 1; else hi = mid;
    }
    lb[g] = lo;
}

// chunked sorted-batch pooling: few atomics per block
__global__ __launch_bounds__(128) void k_pool(const float* __restrict__ x3,
                                              const int* __restrict__ batch,
                                              float* __restrict__ pool, int n) {
    int start = blockIdx.x * 256;
    int end = min(start + 256, n);
    int j = threadIdx.x;
    float acc = 0.f;
    int cur = batch[start];
    for (int v = start; v < end; ++v) {
        int g = batch[v];
        if (g != cur) {
            atomicAdd(&pool[cur * 128 + j], acc);
            acc = 0.f; cur = g;
        }
        acc += x3[(size_t)v * 128 + j];
    }
    atomicAdd(&pool[cur * 128 + j], acc);
}

__global__ __launch_bounds__(128) void k_head(const float* __restrict__ pool,
                                              const int* __restrict__ lb,
                                              const float* __restrict__ fcW1,
                                              const float* __restrict__ fcb1,
                                              const float* __restrict__ fcW2,
                                              const float* __restrict__ fcb2,
                                              float* __restrict__ out) {
    int g = blockIdx.x;
    int j = threadIdx.x;
    __shared__ float ph[128];
    __shared__ float hh[128];
    float cnt = (float)(lb[g + 1] - lb[g]);
    float inv = 1.0f / fmaxf(cnt, 1.0f);
    ph[j] = pool[g * 128 + j] * inv;
    __syncthreads();
    float a = fcb1[j];
    for (int k = 0; k < 128; ++k) a += ph[k] * fcW1[k * 128 + j];
    hh[j] = (a >= 0.f) ? a : 0.01f * a;
    __syncthreads();
    if (j < DDIM) {
        float o = fcb2[j];
        for (int k = 0; k < 128; ++k) o += hh[k] * fcW2[k * DDIM + j];
        float ss = o * o;
        #pragma unroll
        for (int off = 32; off > 0; off >>= 1) ss += __shfl_xor(ss, off);
        float nrm = sqrtf(ss);
        out[g * DDIM + j] = o / fmaxf(nrm, 1e-12f);
    }
}

extern "C" void kernel_launch(void* const* d_in, const int* in_sizes, int n_in,
                              void* d_out, int out_size, void* d_ws, size_t ws_size,
                              hipStream_t stream) {
    const float* x      = (const float*)d_in[0];
    const int*   ei     = (const int*)d_in[1];
    const int*   batch  = (const int*)d_in[2];
    const float* W1     = (const float*)d_in[3];
    const float* b1     = (const float*)d_in[4];
    const float* W2     = (const float*)d_in[5];
    const float* b2     = (const float*)d_in[6];
    const float* W3     = (const float*)d_in[7];
    const float* b3     = (const float*)d_in[8];
    const float* g1     = (const float*)d_in[9];
    const float* be1    = (const float*)d_in[10];
    const float* m1     = (const float*)d_in[11];
    const float* v1     = (const float*)d_in[12];
    const float* g2     = (const float*)d_in[13];
    const float* be2    = (const float*)d_in[14];
    const float* m2     = (const float*)d_in[15];
    const float* v2     = (const float*)d_in[16];
    const float* g3     = (const float*)d_in[17];
    const float* be3    = (const float*)d_in[18];
    const float* m3     = (const float*)d_in[19];
    const float* v3     = (const float*)d_in[20];
    const float* fcW1   = (const float*)d_in[21];
    const float* fcb1   = (const float*)d_in[22];
    const float* fcW2   = (const float*)d_in[23];
    const float* fcb2   = (const float*)d_in[24];
    float* out = (float*)d_out;

    const int N = in_sizes[0] / HDIM;       // 100000
    const int E = in_sizes[1] / 2;          // 1600000
    const int* srcp = ei;
    const int* dstp = ei + E;
    const int scanBlocks = (N + 1023) / 1024;   // 98

    // ---- workspace layout (512B aligned) ----
    char* base = (char*)d_ws;
    size_t off = 0;
    auto alloc = [&](size_t bytes) -> char* {
        char* p = base + off;
        off += (bytes + 511) & ~(size_t)511;
        return p;
    };
    int*   degcnt = (int*)  alloc((size_t)N * 4);
    int*   fill   = (int*)  alloc((size_t)N * 4);
    int*   rowptr = (int*)  alloc((size_t)(N + 4) * 4);
    int*   csrc   = (int*)  alloc((size_t)E * 4);
    float* dinv   = (float*)alloc((size_t)(N + 4) * 4);
    int*   bsum   = (int*)  alloc(128 * 4);
    int*   boff   = (int*)  alloc(128 * 4);
    float* AC     = (float*)alloc(3 * 256 * 4);
    int*   lb     = (int*)  alloc((GDIM + 1) * 4);
    float* pool   = (float*)alloc(GDIM * HDIM * 4);
    float* hs     = (float*)alloc((size_t)N * HDIM * 4);
    float* bufA   = (float*)alloc((size_t)N * HDIM * 4);
    float* bufB   = (float*)alloc((size_t)N * HDIM * 4);
    if (off > ws_size) return;  // workspace too small -> fail validation loudly

    // ---- zero-init counters/accumulators ----
    hipMemsetAsync(degcnt, 0, (size_t)N * 4, stream);
    hipMemsetAsync(fill,   0, (size_t)N * 4, stream);
    hipMemsetAsync(pool,   0, GDIM * HDIM * 4, stream);

    // ---- graph structure (once, reused by all 3 layers) ----
    k_bounds<<<1, 128, 0, stream>>>(batch, N, lb);
    k_count<<<(E + 255) / 256, 256, 0, stream>>>(dstp, E, degcnt);
    k_scan_a<<<scanBlocks, 256, 0, stream>>>(degcnt, bsum, dinv, N);
    k_scan_b<<<1, 128, 0, stream>>>(bsum, scanBlocks, boff, rowptr, N);
    k_scan_c<<<scanBlocks, 256, 0, stream>>>(degcnt, boff, rowptr, N);
    k_fill<<<(E + 255) / 256, 256, 0, stream>>>(srcp, dstp, E, rowptr, fill, csrc);

    // ---- fold bias+BN(eval) into per-channel A,C ----
    k_bnprep<<<3, 128, 0, stream>>>(b1, g1, be1, m1, v1, b2, g2, be2, m2, v2,
                                    b3, g3, be3, m3, v3, AC);

    int gemmBlocks = (N + 63) / 64;
    int aggrBlocks = (N + 3) / 4;

    // layer 1: x -> bufA
    k_gemm_scale<<<gemmBlocks, 512, 0, stream>>>(x, W1, dinv, hs, N);
    k_aggr<<<aggrBlocks, 256, 0, stream>>>(hs, rowptr, csrc, dinv,
                                           AC + 0 * 256, AC + 0 * 256 + 128,
                                           nullptr, bufA, N);
    // layer 2: bufA -> bufB (+bufA residual)
    k_gemm_scale<<<gemmBlocks, 512, 0, stream>>>(bufA, W2, dinv, hs, N);
    k_aggr<<<aggrBlocks, 256, 0, stream>>>(hs, rowptr, csrc, dinv,
                                           AC + 1 * 256, AC + 1 * 256 + 128,
                                           bufA, bufB, N);
    // layer 3: bufB -> bufA (+bufB residual)
    k_gemm_scale<<<gemmBlocks, 512, 0, stream>>>(bufB, W3, dinv, hs, N);
    k_aggr<<<aggrBlocks, 256, 0, stream>>>(hs, rowptr, csrc, dinv,
                                           AC + 2 * 256, AC + 2 * 256 + 128,
                                           bufB, bufA, N);

    // ---- pool + head ----
    k_pool<<<(N + 255) / 256, 128, 0, stream>>>(bufA, batch, pool, N);
    k_head<<<GDIM, 128, 0, stream>>>(pool, lb, fcW1, fcb1, fcW2, fcb2, out);
}